// Round 9
// baseline (377.488 us; speedup 1.0000x reference)
//
#include <hip/hip_runtime.h>

#define B_SZ   8
#define S_LEN  4096
#define D_K    128
#define KB     64      // keys per step
// R8 schedule: 256-query tiles (16 per batch). Tile t needs 4t+4 key-steps.
// Split-K chunks of 8 steps: 512 full 8-step chunks + 64 4-step tails = 576.
#define NFULL  512
#define NCHUNK 576

typedef short  short8  __attribute__((ext_vector_type(8)));
typedef float  floatx4 __attribute__((ext_vector_type(4)));

#define EXP2F(x) exp2f(x)

__device__ __forceinline__ unsigned bfround(float x) {
  unsigned u = __builtin_bit_cast(unsigned, x);
  return (u + 0x7fffu + ((u >> 16) & 1u)) >> 16;
}
__device__ __forceinline__ unsigned bfpack2(float a, float b) {
  return bfround(a) | (bfround(b) << 16);
}
// single-instruction RTNE pack (hot loop only; numerics validated R1-R7)
__device__ __forceinline__ unsigned cvtpk(float lo, float hi) {
  unsigned r;
  asm("v_cvt_pk_bf16_f32 %0, %1, %2" : "=v"(r) : "v"(lo), "v"(hi));
  return r;
}

// NOTE (R6): permlane16/32_swap reductions failed correctness (absmax 4.4).
// __shfl_xor path only. Do not reintroduce without isolated validation.

// Async global->LDS DMA, 16B per lane (wave writes 1024B contiguous LDS;
// LDS dest is wave-uniform base, HW adds lane*16 — R3-R7 proven).
__device__ __forceinline__ void dma16(const void* g, const void* l) {
  __builtin_amdgcn_global_load_lds(
      (__attribute__((address_space(1))) unsigned int*)(unsigned long long)g,
      (__attribute__((address_space(3))) unsigned int*)(unsigned int)(unsigned long long)l,
      16, 0, 0);
}

// ======================= pre-pass: tile-image builder (R3-R7 proven) =======================
// One block per (b, step s): K and V^T as 16KB tile IMAGES with the XOR
// bank-swizzle baked in (byte ^= ((row&7)<<4)); worker DMAs them linearly.

__global__ __launch_bounds__(256)
void prep(const float* __restrict__ K, const float* __restrict__ V,
          unsigned short* __restrict__ Kb, unsigned short* __restrict__ Vt) {
  __shared__ float tile[64][129];
  const int tid = threadIdx.x;
  const int bid = blockIdx.x;         // b*64 + s
  const int b   = bid >> 6;
  const int s   = bid & 63;
  const int kt  = s * 64;

  // ---- K tile image ----
  {
    const int r  = tid >> 2;
    const int cq = tid & 3;
    const float* kp = K + (size_t)(b * S_LEN + kt + r) * D_K + cq * 32;
    unsigned short* kdst = Kb + (size_t)bid * 8192 + r * 128;
    const int xr = (r & 7) << 4;
#pragma unroll
    for (int jj = 0; jj < 4; ++jj) {
      float4 f0 = *(const float4*)(kp + jj * 8);
      float4 f1 = *(const float4*)(kp + jj * 8 + 4);
      uint4 u;
      u.x = bfpack2(f0.x, f0.y);
      u.y = bfpack2(f0.z, f0.w);
      u.z = bfpack2(f1.x, f1.y);
      u.w = bfpack2(f1.z, f1.w);
      const int o = (cq * 64 + jj * 16) ^ xr;
      *(uint4*)(kdst + (o >> 1)) = u;
    }
  }

  // ---- V tile: load to LDS f32 ----
  {
    const int k  = tid >> 2;
    const int cq = tid & 3;
    const float* vp = V + (size_t)(b * S_LEN + kt + k) * D_K + cq * 32;
#pragma unroll
    for (int i = 0; i < 8; ++i) {
      float4 f = *(const float4*)(vp + i * 4);
      tile[k][cq * 32 + i * 4]     = f.x;
      tile[k][cq * 32 + i * 4 + 1] = f.y;
      tile[k][cq * 32 + i * 4 + 2] = f.z;
      tile[k][cq * 32 + i * 4 + 3] = f.w;
    }
  }
  __syncthreads();

  // ---- V^T tile image (transposed + swizzled) ----
  {
    const int d = tid >> 1;
    const int h = tid & 1;
    unsigned short* vdst = Vt + (size_t)bid * 8192 + d * 64;
    const int xr = (d & 7) << 4;
#pragma unroll
    for (int jj = 0; jj < 4; ++jj) {
      const int k0 = h * 32 + jj * 8;
      uint4 u;
      u.x = bfpack2(tile[k0 + 0][d], tile[k0 + 1][d]);
      u.y = bfpack2(tile[k0 + 2][d], tile[k0 + 3][d]);
      u.z = bfpack2(tile[k0 + 4][d], tile[k0 + 5][d]);
      u.w = bfpack2(tile[k0 + 6][d], tile[k0 + 7][d]);
      const int o = (h * 64 + jj * 16) ^ xr;
      *(uint4*)(vdst + (o >> 1)) = u;
    }
  }
}

// ======================= worker kernel =======================
// R8 (resubmit): 8 waves (512 thr), 256-query tile, 2 blocks/CU -> 4 waves/
// SIMD (2x R7 TLP). DMA double-buffer pipeline (counted vmcnt(4), raw
// s_barrier). P is staged through Klds[cur] (dead after QK^T; post-QKT
// barrier makes it safe; wave-private stride-64 rows with XOR swizzle) ->
// LDS = 65,536B exactly. Static schedule: block == chunk (576 blocks; 512
// full 8-step + 64 4-step tails dispatched last = LPT). Bijective XCD
// swizzle + batch-major grouping for tile-image L2 reuse. slot == wid.

__global__ __launch_bounds__(512, 4)
void attn_worker(const float* __restrict__ Q, const unsigned short* __restrict__ Kb,
                 const unsigned short* __restrict__ Vt,
                 float* __restrict__ ml, float* __restrict__ pO) {
  __shared__ __align__(16) short Klds[2][8192];          // 2 x 16KB (also P scratch)
  __shared__ __align__(16) short Vtlds[2][8192];         // 2 x 16KB

  const int tid  = threadIdx.x;
  const int lane = tid & 63;
  const int w    = tid >> 6;        // wave 0..7
  const int l15  = lane & 15;
  const int quad = lane >> 4;
  const int xk   = (l15 & 7) << 3;  // short-index XOR for swizzled LDS reads

  const float CSC = 0.12752041f;    // log2(e)/sqrt(128)

  // ---- bijective XCD swizzle (576 = 8*72): XCD gets contiguous work ids ----
  const int orig = blockIdx.x;
  const int wid  = (orig & 7) * 72 + (orig >> 3);

  // ---- decode wid -> (b, tile t, chunk step range) ----
  int b, t, s0, s1;
  if (wid < NFULL) {                       // full 8-step chunks, batch-major
    b = wid >> 6;
    int r = wid & 63;                      // 0..63; nf(t) = (t+1)>>1
    t = 15;
    while (r >= ((t + 1) >> 1)) { r -= (t + 1) >> 1; --t; }
    s0 = r * 8;  s1 = s0 + 8;
  } else {                                 // 4-step tails (t even), last chunk
    const int rc = wid - NFULL;            // 0..63
    b = rc >> 3;
    t = 14 - 2 * (rc & 7);
    s0 = 4 * t;  s1 = s0 + 4;
  }
  const int q0 = t << 8;

  // ---- Q fragments for 2 subtiles (B-operand: n=l15=query, k=quad*8+i=d) ----
  short8 bq[2][4];
  int qg[2];
#pragma unroll
  for (int sub = 0; sub < 2; ++sub) {
    qg[sub] = q0 + w * 32 + sub * 16 + l15;
    const float* qrow = Q + (size_t)(b * S_LEN + qg[sub]) * D_K + quad * 8;
#pragma unroll
    for (int kd = 0; kd < 4; ++kd) {
      float4 f0 = *(const float4*)(qrow + kd * 32);
      float4 f1 = *(const float4*)(qrow + kd * 32 + 4);
      union { short8 s; unsigned u[4]; } tt;
      tt.u[0] = bfpack2(f0.x, f0.y);
      tt.u[1] = bfpack2(f0.z, f0.w);
      tt.u[2] = bfpack2(f1.x, f1.y);
      tt.u[3] = bfpack2(f1.z, f1.w);
      bq[sub][kd] = tt.s;
    }
  }

  floatx4 acc[2][8];
#pragma unroll
  for (int sub = 0; sub < 2; ++sub)
#pragma unroll
    for (int nc = 0; nc < 8; ++nc) acc[sub][nc] = (floatx4){0.f, 0.f, 0.f, 0.f};
  float m_run[2] = {-1e30f, -1e30f}, l_run[2] = {0.f, 0.f};

  const unsigned short* kb0 = Kb + (size_t)b * 64 * 8192;   // tile images
  const unsigned short* vb0 = Vt + (size_t)b * 64 * 8192;
  const int lo = lane * 8;            // lane*16B in shorts

  // stage(buf, step): each wave DMAs 1/8 of K and V (2KB+2KB) = 4 instrs
#define STAGE(BUF, S)                                                          \
  do {                                                                         \
    const unsigned short* kg_ = kb0 + (size_t)(S) * 8192 + w * 1024 + lo;      \
    const unsigned short* vg_ = vb0 + (size_t)(S) * 8192 + w * 1024 + lo;      \
    short* kl_ = &Klds[BUF][w * 1024];                                         \
    short* vl_ = &Vtlds[BUF][w * 1024];                                        \
    dma16(kg_, kl_);        dma16(kg_ + 512, kl_ + 512);                       \
    dma16(vg_, vl_);        dma16(vg_ + 512, vl_ + 512);                       \
  } while (0)

  // ---- prologue: stage s0 (and s0+1 into the other buffer) ----
  STAGE(s0 & 1, s0);
  if (s0 + 1 < s1) {
    STAGE((s0 + 1) & 1, s0 + 1);
    asm volatile("s_waitcnt vmcnt(4)" ::: "memory");   // s0's 4 done
  } else {
    asm volatile("s_waitcnt vmcnt(0)" ::: "memory");
  }
  __builtin_amdgcn_s_barrier();
  __builtin_amdgcn_sched_barrier(0);

  for (int s = s0; s < s1; ++s) {
    const int kt  = s * KB;
    const int cur = s & 1;
    const short* Kl = &Klds[cur][0];
    const short* Vl = &Vtlds[cur][0];
    const bool act = (kt <= q0 + w * 32 + 31);   // wave fully masked beyond

    floatx4 st[2][4];
    if (act) {
      // ---- S^T = K*Q^T for both subtiles; each A-frag read used twice ----
      __builtin_amdgcn_s_setprio(1);
#pragma unroll
      for (int kf = 0; kf < 4; ++kf) {
        floatx4 c0 = (floatx4){0.f, 0.f, 0.f, 0.f};
        floatx4 c1 = (floatx4){0.f, 0.f, 0.f, 0.f};
#pragma unroll
        for (int kd = 0; kd < 4; ++kd) {
          short8 a = *(const short8*)(&Kl[((kf * 16 + l15) << 7) + ((kd * 32 + quad * 8) ^ xk)]);
          c0 = __builtin_amdgcn_mfma_f32_16x16x32_bf16(a, bq[0][kd], c0, 0, 0, 0);
          c1 = __builtin_amdgcn_mfma_f32_16x16x32_bf16(a, bq[1][kd], c1, 0, 0, 0);
        }
        st[0][kf] = c0;
        st[1][kf] = c1;
      }
      __builtin_amdgcn_s_setprio(0);

      // ---- causal mask (boundary subtiles only) ----
#pragma unroll
      for (int sub = 0; sub < 2; ++sub) {
        if (kt + 63 > q0 + w * 32 + sub * 16) {
#pragma unroll
          for (int kf = 0; kf < 4; ++kf)
#pragma unroll
            for (int r = 0; r < 4; ++r) {
              int key = kt + kf * 16 + quad * 4 + r;
              if (key > qg[sub]) st[sub][kf][r] = -1e30f;
            }
        }
      }
    }

    // K[cur] fully consumed block-wide; its buffer becomes P scratch.
    __builtin_amdgcn_s_barrier();
    __builtin_amdgcn_sched_barrier(0);

    short8 pa[2][2];
    if (act) {
      // ---- online softmax + P roundtrip (through Klds[cur]) per subtile ----
      short* pw = &Klds[cur][(w * 16 + l15) << 6];   // wave-private 64-short row
#pragma unroll
      for (int sub = 0; sub < 2; ++sub) {
        float mx = st[sub][0][0];
#pragma unroll
        for (int kf = 0; kf < 4; ++kf)
#pragma unroll
          for (int r = 0; r < 4; ++r) mx = fmaxf(mx, st[sub][kf][r]);
        mx = fmaxf(mx, __shfl_xor(mx, 16, 64));
        mx = fmaxf(mx, __shfl_xor(mx, 32, 64));
        const float m_new = fmaxf(m_run[sub], mx);
        const bool  grow  = __any(m_new > m_run[sub]);

        float p[4][4];
        float tsum = 0.f;
#pragma unroll
        for (int kf = 0; kf < 4; ++kf)
#pragma unroll
          for (int r = 0; r < 4; ++r) {
            p[kf][r] = EXP2F((st[sub][kf][r] - m_new) * CSC);
            tsum += p[kf][r];
          }
        tsum += __shfl_xor(tsum, 16, 64);
        tsum += __shfl_xor(tsum, 32, 64);

        if (grow) {
          const float alpha = EXP2F((m_run[sub] - m_new) * CSC);
          l_run[sub] = l_run[sub] * alpha + tsum;
#pragma unroll
          for (int r = 0; r < 4; ++r) {
            const float ar = __shfl(alpha, quad * 4 + r, 64);
#pragma unroll
            for (int nc = 0; nc < 8; ++nc) acc[sub][nc][r] *= ar;
          }
        } else {
          l_run[sub] = l_run[sub] + tsum;   // m_new == m_run for every query
        }
        m_run[sub] = m_new;

        // P: C-layout -> A-layout; XOR-swizzled stride-64 rows (in-order per wave)
#pragma unroll
        for (int kf = 0; kf < 4; ++kf) {
          uint2 u;
          u.x = cvtpk(p[kf][0], p[kf][1]);
          u.y = cvtpk(p[kf][2], p[kf][3]);
          *(uint2*)(&pw[(kf * 16 + quad * 4) ^ xk]) = u;
        }
        __asm__ __volatile__("" ::: "memory");
        pa[sub][0] = *(const short8*)(&pw[(quad * 8) ^ xk]);
        pa[sub][1] = *(const short8*)(&pw[(32 + quad * 8) ^ xk]);
        __asm__ __volatile__("" ::: "memory");
      }

      // ---- O += P*V ; each B-frag read used by both subtiles ----
      __builtin_amdgcn_s_setprio(1);
#pragma unroll
      for (int nc = 0; nc < 8; ++nc) {
        short8 bv0 = *(const short8*)(&Vl[((nc * 16 + l15) << 6) + ((quad * 8) ^ xk)]);
        short8 bv1 = *(const short8*)(&Vl[((nc * 16 + l15) << 6) + ((32 + quad * 8) ^ xk)]);
        acc[0][nc] = __builtin_amdgcn_mfma_f32_16x16x32_bf16(pa[0][0], bv0, acc[0][nc], 0, 0, 0);
        acc[0][nc] = __builtin_amdgcn_mfma_f32_16x16x32_bf16(pa[0][1], bv1, acc[0][nc], 0, 0, 0);
        acc[1][nc] = __builtin_amdgcn_mfma_f32_16x16x32_bf16(pa[1][0], bv0, acc[1][nc], 0, 0, 0);
        acc[1][nc] = __builtin_amdgcn_mfma_f32_16x16x32_bf16(pa[1][1], bv1, acc[1][nc], 0, 0, 0);
      }
      __builtin_amdgcn_s_setprio(0);
    }

    // ---- pipeline advance: free both [cur] buffers, stage s+2, await s+1 ----
    asm volatile("s_waitcnt lgkmcnt(0)" ::: "memory");
    __builtin_amdgcn_s_barrier();               // all waves done with P/V[cur]
    __builtin_amdgcn_sched_barrier(0);
    if (s + 2 < s1) {
      STAGE(cur, s + 2);
      asm volatile("s_waitcnt vmcnt(4)" ::: "memory");   // s+1's 4 done
    } else if (s + 1 < s1) {
      asm volatile("s_waitcnt vmcnt(0)" ::: "memory");
    }
    __builtin_amdgcn_s_barrier();               // buf[(s+1)&1] visible to all
    __builtin_amdgcn_sched_barrier(0);
  }
#undef STAGE

  // ---- partial epilogue: unnormalized O + (m,l); slot == wid ----
  float* po = pO + (size_t)wid * 32768;
#pragma unroll
  for (int sub = 0; sub < 2; ++sub) {
#pragma unroll
    for (int r = 0; r < 4; ++r) {
      const int qrow = w * 32 + sub * 16 + quad * 4 + r;
      float* op = po + qrow * D_K + l15;
#pragma unroll
      for (int nc = 0; nc < 8; ++nc) op[nc * 16] = acc[sub][nc][r];
    }
    if (quad == 0) {
      const int qrow = w * 32 + sub * 16 + l15;
      ml[(size_t)wid * 512 + qrow * 2]     = m_run[sub];
      ml[(size_t)wid * 512 + qrow * 2 + 1] = l_run[sub];
    }
  }
}

// ======================= combine kernel =======================
// 256 blocks = (b*16 + t)*2 + d-half; up to 8 partials per 256-q tile.

__global__ __launch_bounds__(256)
void attn_combine(const float* __restrict__ ml, const float* __restrict__ pO,
                  float* __restrict__ O) {
  const int cb   = blockIdx.x;
  const int half = cb & 1;
  const int bt   = cb >> 1;
  const int b    = bt >> 4;
  const int t    = bt & 15;
  const float CSC = 0.12752041f;

  const int q  = threadIdx.x;         // 0..255
  const int dh = half * 64;

  // chunk slots for (b, t): nf full chunks + tail (t even)
  int cum = 0;
  for (int tt = 15; tt > t; --tt) cum += (tt + 1) >> 1;
  const int nf = (t + 1) >> 1;
  int slots[8];
  int ns = 0;
#pragma unroll
  for (int jj = 0; jj < 8; ++jj)
    if (jj < nf) { slots[ns] = b * 64 + cum + jj; ++ns; }
  if (!(t & 1)) { slots[ns] = NFULL + b * 8 + (7 - (t >> 1)); ++ns; }

  float m[8], l[8], wgt[8];
  float M = -1e30f;
#pragma unroll
  for (int i = 0; i < 8; ++i) {
    if (i < ns) {
      m[i] = ml[(size_t)slots[i] * 512 + q * 2];
      l[i] = ml[(size_t)slots[i] * 512 + q * 2 + 1];
      M = fmaxf(M, m[i]);
    }
  }
  float L = 0.f;
#pragma unroll
  for (int i = 0; i < 8; ++i)
    if (i < ns) { wgt[i] = EXP2F((m[i] - M) * CSC); L += wgt[i] * l[i]; }
  const float inv = 1.0f / L;

  float4 out[16];
#pragma unroll
  for (int v = 0; v < 16; ++v) out[v] = make_float4(0.f, 0.f, 0.f, 0.f);
#pragma unroll
  for (int i = 0; i < 8; ++i) {
    if (i < ns) {
      const float* src = pO + (size_t)slots[i] * 32768 + q * D_K + dh;
      const float wj = wgt[i];
#pragma unroll
      for (int v = 0; v < 16; ++v) {
        float4 f = *(const float4*)(src + v * 4);
        out[v].x += wj * f.x;  out[v].y += wj * f.y;
        out[v].z += wj * f.z;  out[v].w += wj * f.w;
      }
    }
  }
  float* dst = O + ((size_t)(b * S_LEN) + t * 256 + q) * D_K + dh;
#pragma unroll
  for (int v = 0; v < 16; ++v) {
    *(float4*)(dst + v * 4) = make_float4(out[v].x * inv, out[v].y * inv,
                                          out[v].z * inv, out[v].w * inv);
  }
}

// ======================= fallback (known-good, ws-too-small path) =======================

#define KT_STR 136
#define VT_STR 72
#define PT_STR 72

__global__ __launch_bounds__(256, 2)
void attn_fwd_fb(const float* __restrict__ Q, const float* __restrict__ K,
                 const float* __restrict__ V, float* __restrict__ O) {
  __shared__ __align__(16) short Klds[KB * KT_STR];
  __shared__ __align__(16) short Vtlds[D_K * VT_STR];
  __shared__ __align__(16) short Plds[4 * 16 * PT_STR];

  const int tid  = threadIdx.x;
  const int lane = tid & 63;
  const int w    = tid >> 6;
  const int l15  = lane & 15;
  const int quad = lane >> 4;

  const int bid = blockIdx.x;
  const int b   = bid & 7;
  const int qi  = 63 - (bid >> 3);
  const int q0  = qi * 64;

  const float CSC = 0.12752041f;

  const int    qg   = q0 + w * 16 + l15;
  const float* qrow = Q + (size_t)(b * S_LEN + qg) * D_K + quad * 8;
  short8 bq[4];
#pragma unroll
  for (int kd = 0; kd < 4; ++kd) {
    float4 f0 = *(const float4*)(qrow + kd * 32);
    float4 f1 = *(const float4*)(qrow + kd * 32 + 4);
    union { short8 s; unsigned u[4]; } t;
    t.u[0] = bfpack2(f0.x, f0.y);
    t.u[1] = bfpack2(f0.z, f0.w);
    t.u[2] = bfpack2(f1.x, f1.y);
    t.u[3] = bfpack2(f1.z, f1.w);
    bq[kd] = t.s;
  }

  floatx4 acc[8];
#pragma unroll
  for (int nc = 0; nc < 8; ++nc) acc[nc] = (floatx4){0.f, 0.f, 0.f, 0.f};
  float m_run = -1e30f, l_run = 0.f;

  const int d4 = tid & 31;
  const int kq = tid >> 5;
  const int nsteps = qi + 1;

  for (int s = 0; s < nsteps; ++s) {
    const int kt = s * KB;
#pragma unroll
    for (int r2 = 0; r2 < 2; ++r2) {
      const int row = r2 * 32 + kq * 4;
      const float* kp = K + (size_t)(b * S_LEN + kt + row) * D_K + d4 * 4;
      const float* vp = V + (size_t)(b * S_LEN + kt + row) * D_K + d4 * 4;
      float4 fk[4], fv[4];
#pragma unroll
      for (int i = 0; i < 4; ++i) {
        fk[i] = *(const float4*)(kp + i * D_K);
        fv[i] = *(const float4*)(vp + i * D_K);
      }
#pragma unroll
      for (int i = 0; i < 4; ++i) {
        uint2 u;
        u.x = bfpack2(fk[i].x, fk[i].y);
        u.y = bfpack2(fk[i].z, fk[i].w);
        *(uint2*)(&Klds[(row + i) * KT_STR + d4 * 4]) = u;
      }
#pragma unroll
      for (int c = 0; c < 4; ++c) {
        float e0 = ((const float*)&fv[0])[c];
        float e1 = ((const float*)&fv[1])[c];
        float e2 = ((const float*)&fv[2])[c];
        float e3 = ((const float*)&fv[3])[c];
        uint2 u;
        u.x = bfpack2(e0, e1);
        u.y = bfpack2(e2, e3);
        *(uint2*)(&Vtlds[(d4 * 4 + c) * VT_STR + row]) = u;
      }
    }
    __syncthreads();

    floatx4 st[4];
#pragma unroll
    for (int kf = 0; kf < 4; ++kf) {
      floatx4 cc = (floatx4){0.f, 0.f, 0.f, 0.f};
#pragma unroll
      for (int kd = 0; kd < 4; ++kd) {
        short8 a = *(const short8*)(&Klds[(kf * 16 + l15) * KT_STR + kd * 32 + quad * 8]);
        cc = __builtin_amdgcn_mfma_f32_16x16x32_bf16(a, bq[kd], cc, 0, 0, 0);
      }
      st[kf] = cc;
    }

    if (s == nsteps - 1) {
#pragma unroll
      for (int kf = 0; kf < 4; ++kf)
#pragma unroll
        for (int rr = 0; rr < 4; ++rr) {
          int key = kt + kf * 16 + quad * 4 + rr;
          if (key > qg) st[kf][rr] = -1e30f;
        }
    }

    float mx = st[0][0];
#pragma unroll
    for (int kf = 0; kf < 4; ++kf)
#pragma unroll
      for (int rr = 0; rr < 4; ++rr) mx = fmaxf(mx, st[kf][rr]);
    mx = fmaxf(mx, __shfl_xor(mx, 16, 64));
    mx = fmaxf(mx, __shfl_xor(mx, 32, 64));
    const float m_new = fmaxf(m_run, mx);
    const float alpha = EXP2F((m_run - m_new) * CSC);

    float p[4][4];
    float tsum = 0.f;
#pragma unroll
    for (int kf = 0; kf < 4; ++kf)
#pragma unroll
      for (int rr = 0; rr < 4; ++rr) {
        p[kf][rr] = EXP2F((st[kf][rr] - m_new) * CSC);
        tsum += p[kf][rr];
      }
    tsum += __shfl_xor(tsum, 16, 64);
    tsum += __shfl_xor(tsum, 32, 64);
    l_run = l_run * alpha + tsum;
    m_run = m_new;

#pragma unroll
    for (int rr = 0; rr < 4; ++rr) {
      const float ar = __shfl(alpha, quad * 4 + rr, 64);
#pragma unroll
      for (int nc = 0; nc < 8; ++nc) acc[nc][rr] *= ar;
    }

    short* pw = &Plds[(w * 16 + l15) * PT_STR];
#pragma unroll
    for (int kf = 0; kf < 4; ++kf) {
      uint2 u;
      u.x = bfpack2(p[kf][0], p[kf][1]);
      u.y = bfpack2(p[kf][2], p[kf][3]);
      *(uint2*)(&pw[kf * 16 + quad * 4]) = u;
    }
    __asm__ __volatile__("" ::: "memory");
    short8 pa0 = *(const short8*)(&pw[quad * 8]);
    short8 pa1 = *(const short8*)(&pw[32 + quad * 8]);

#pragma unroll
    for (int nc = 0; nc < 8; ++nc) {
      short8 bv0 = *(const short8*)(&Vtlds[(nc * 16 + l15) * VT_STR + quad * 8]);
      acc[nc] = __builtin_amdgcn_mfma_f32_16x16x32_bf16(pa0, bv0, acc[nc], 0, 0, 0);
      short8 bv1 = *(const short8*)(&Vtlds[(nc * 16 + l15) * VT_STR + 32 + quad * 8]);
      acc[nc] = __builtin_amdgcn_mfma_f32_16x16x32_bf16(pa1, bv1, acc[nc], 0, 0, 0);
    }
    __syncthreads();
  }

#pragma unroll
  for (int rr = 0; rr < 4; ++rr) {
    const float lr  = __shfl(l_run, quad * 4 + rr, 64);
    const float inv = 1.0f / lr;
    const int qout  = q0 + w * 16 + quad * 4 + rr;
    float* op = O + (size_t)(b * S_LEN + qout) * D_K + l15;
#pragma unroll
    for (int nc = 0; nc < 8; ++nc) op[nc * 16] = acc[nc][rr] * inv;
  }
}

// ======================= launch =======================

extern "C" void kernel_launch(void* const* d_in, const int* in_sizes, int n_in,
                              void* d_out, int out_size, void* d_ws, size_t ws_size,
                              hipStream_t stream) {
  const float* Q = (const float*)d_in[0];
  const float* K = (const float*)d_in[1];
  const float* V = (const float*)d_in[2];
  float* O = (float*)d_out;

  const size_t elems = (size_t)B_SZ * S_LEN * D_K;   // 4.19M

  // ws layout (bytes):
  //   0          : ml    [576 slots][256 q][m,l]      =  1,179,648
  //   1,179,648  : partO [576 slots][256 q][128 d]f32 = 75,497,472
  //   76,677,120 : Kb tile-images bf16                =  8,388,608
  //   85,065,728 : Vt tile-images bf16                =  8,388,608
  //   need ~93.5 MB
  const size_t off_ml = 0;
  const size_t off_po = (size_t)NCHUNK * 512 * 4;
  const size_t off_kb = off_po + (size_t)NCHUNK * 32768 * 4;
  const size_t off_vt = off_kb + elems * 2;
  const size_t need   = off_vt + elems * 2;

  if (ws_size >= need) {
    char* ws = (char*)d_ws;
    float*          mlp = (float*)(ws + off_ml);
    float*          po  = (float*)(ws + off_po);
    unsigned short* Kbp = (unsigned short*)(ws + off_kb);
    unsigned short* Vtp = (unsigned short*)(ws + off_vt);

    prep<<<dim3(B_SZ * 64), dim3(256), 0, stream>>>(K, V, Kbp, Vtp);
    attn_worker<<<dim3(NCHUNK), dim3(512), 0, stream>>>(Q, Kbp, Vtp, mlp, po);
    attn_combine<<<dim3(256), dim3(256), 0, stream>>>(mlp, po, O);
  } else {
    attn_fwd_fb<<<dim3(512), dim3(256), 0, stream>>>(Q, K, V, O);
  }
}

// Round 10
// 215.285 us; speedup vs baseline: 1.7534x; 1.7534x over previous
//
#include <hip/hip_runtime.h>

#define B_SZ   8
#define S_LEN  4096
#define D_K    128
#define KB     64      // keys per step
// 256-query tiles (16 per batch). Tile t needs 4t+4 key-steps.
// Split-K chunks of 8 steps: 512 full 8-step chunks + 64 4-step tails = 576.
#define NFULL  512
#define NCHUNK 576

typedef short  short8  __attribute__((ext_vector_type(8)));
typedef float  floatx4 __attribute__((ext_vector_type(4)));

#define EXP2F(x) exp2f(x)

__device__ __forceinline__ unsigned bfround(float x) {
  unsigned u = __builtin_bit_cast(unsigned, x);
  return (u + 0x7fffu + ((u >> 16) & 1u)) >> 16;
}
__device__ __forceinline__ unsigned bfpack2(float a, float b) {
  return bfround(a) | (bfround(b) << 16);
}
// single-instruction RTNE pack (hot loop only; numerics validated R1-R9)
__device__ __forceinline__ unsigned cvtpk(float lo, float hi) {
  unsigned r;
  asm("v_cvt_pk_bf16_f32 %0, %1, %2" : "=v"(r) : "v"(lo), "v"(hi));
  return r;
}

// NOTE (R6): permlane16/32_swap reductions failed correctness (absmax 4.4).
// __shfl_xor path only. Do not reintroduce without isolated validation.
// NOTE (R9): on this toolchain __launch_bounds__ 2nd arg behaves as min
// BLOCKS PER CU for multi-wave blocks: (512,4) -> 8 waves/SIMD -> VGPR cap 64
// -> 474MB spill. (512,2) -> 4 waves/SIMD -> cap 128, fits the ~104 set.

// Async global->LDS DMA, 16B per lane (wave writes 1024B contiguous LDS;
// LDS dest is wave-uniform base, HW adds lane*16 — R3-R9 proven).
__device__ __forceinline__ void dma16(const void* g, const void* l) {
  __builtin_amdgcn_global_load_lds(
      (__attribute__((address_space(1))) unsigned int*)(unsigned long long)g,
      (__attribute__((address_space(3))) unsigned int*)(unsigned int)(unsigned long long)l,
      16, 0, 0);
}

// ======================= pre-pass: tile-image builder (R3-R9 proven) =======================
// One block per (b, step s): K and V^T as 16KB tile IMAGES with the XOR
// bank-swizzle baked in (byte ^= ((row&7)<<4)); worker DMAs them linearly.

__global__ __launch_bounds__(256)
void prep(const float* __restrict__ K, const float* __restrict__ V,
          unsigned short* __restrict__ Kb, unsigned short* __restrict__ Vt) {
  __shared__ float tile[64][129];
  const int tid = threadIdx.x;
  const int bid = blockIdx.x;         // b*64 + s
  const int b   = bid >> 6;
  const int s   = bid & 63;
  const int kt  = s * 64;

  // ---- K tile image ----
  {
    const int r  = tid >> 2;
    const int cq = tid & 3;
    const float* kp = K + (size_t)(b * S_LEN + kt + r) * D_K + cq * 32;
    unsigned short* kdst = Kb + (size_t)bid * 8192 + r * 128;
    const int xr = (r & 7) << 4;
#pragma unroll
    for (int jj = 0; jj < 4; ++jj) {
      float4 f0 = *(const float4*)(kp + jj * 8);
      float4 f1 = *(const float4*)(kp + jj * 8 + 4);
      uint4 u;
      u.x = bfpack2(f0.x, f0.y);
      u.y = bfpack2(f0.z, f0.w);
      u.z = bfpack2(f1.x, f1.y);
      u.w = bfpack2(f1.z, f1.w);
      const int o = (cq * 64 + jj * 16) ^ xr;
      *(uint4*)(kdst + (o >> 1)) = u;
    }
  }

  // ---- V tile: load to LDS f32 ----
  {
    const int k  = tid >> 2;
    const int cq = tid & 3;
    const float* vp = V + (size_t)(b * S_LEN + kt + k) * D_K + cq * 32;
#pragma unroll
    for (int i = 0; i < 8; ++i) {
      float4 f = *(const float4*)(vp + i * 4);
      tile[k][cq * 32 + i * 4]     = f.x;
      tile[k][cq * 32 + i * 4 + 1] = f.y;
      tile[k][cq * 32 + i * 4 + 2] = f.z;
      tile[k][cq * 32 + i * 4 + 3] = f.w;
    }
  }
  __syncthreads();

  // ---- V^T tile image (transposed + swizzled) ----
  {
    const int d = tid >> 1;
    const int h = tid & 1;
    unsigned short* vdst = Vt + (size_t)bid * 8192 + d * 64;
    const int xr = (d & 7) << 4;
#pragma unroll
    for (int jj = 0; jj < 4; ++jj) {
      const int k0 = h * 32 + jj * 8;
      uint4 u;
      u.x = bfpack2(tile[k0 + 0][d], tile[k0 + 1][d]);
      u.y = bfpack2(tile[k0 + 2][d], tile[k0 + 3][d]);
      u.z = bfpack2(tile[k0 + 4][d], tile[k0 + 5][d]);
      u.w = bfpack2(tile[k0 + 6][d], tile[k0 + 7][d]);
      const int o = (h * 64 + jj * 16) ^ xr;
      *(uint4*)(vdst + (o >> 1)) = u;
    }
  }
}

// ======================= worker kernel =======================
// R10 = R9 with the launch-bounds fix: 8 waves (512 thr), 256-query tile,
// __launch_bounds__(512,2) -> 2 blocks/CU, 4 waves/SIMD, VGPR cap 128 (no
// spill). DMA double-buffer pipeline (counted vmcnt(4), raw s_barrier). P is
// staged through Klds[cur] (dead after QK^T; post-QKT barrier; wave-private
// XOR-swizzled stride-64 rows) -> LDS = 65,536B. Static schedule: block ==
// chunk (576; full chunks first, 4-step tails last = LPT). Bijective XCD
// swizzle + batch-major grouping for tile-image L2 reuse. slot == wid.

__global__ __launch_bounds__(512, 2)
void attn_worker(const float* __restrict__ Q, const unsigned short* __restrict__ Kb,
                 const unsigned short* __restrict__ Vt,
                 float* __restrict__ ml, float* __restrict__ pO) {
  __shared__ __align__(16) short Klds[2][8192];          // 2 x 16KB (also P scratch)
  __shared__ __align__(16) short Vtlds[2][8192];         // 2 x 16KB

  const int tid  = threadIdx.x;
  const int lane = tid & 63;
  const int w    = tid >> 6;        // wave 0..7
  const int l15  = lane & 15;
  const int quad = lane >> 4;
  const int xk   = (l15 & 7) << 3;  // short-index XOR for swizzled LDS reads

  const float CSC = 0.12752041f;    // log2(e)/sqrt(128)

  // ---- bijective XCD swizzle (576 = 8*72): XCD gets contiguous work ids ----
  const int orig = blockIdx.x;
  const int wid  = (orig & 7) * 72 + (orig >> 3);

  // ---- decode wid -> (b, tile t, chunk step range) ----
  int b, t, s0, s1;
  if (wid < NFULL) {                       // full 8-step chunks, batch-major
    b = wid >> 6;
    int r = wid & 63;                      // 0..63; nf(t) = (t+1)>>1
    t = 15;
    while (r >= ((t + 1) >> 1)) { r -= (t + 1) >> 1; --t; }
    s0 = r * 8;  s1 = s0 + 8;
  } else {                                 // 4-step tails (t even), last chunk
    const int rc = wid - NFULL;            // 0..63
    b = rc >> 3;
    t = 14 - 2 * (rc & 7);
    s0 = 4 * t;  s1 = s0 + 4;
  }
  const int q0 = t << 8;

  // ---- Q fragments for 2 subtiles (B-operand: n=l15=query, k=quad*8+i=d) ----
  short8 bq[2][4];
  int qg[2];
#pragma unroll
  for (int sub = 0; sub < 2; ++sub) {
    qg[sub] = q0 + w * 32 + sub * 16 + l15;
    const float* qrow = Q + (size_t)(b * S_LEN + qg[sub]) * D_K + quad * 8;
#pragma unroll
    for (int kd = 0; kd < 4; ++kd) {
      float4 f0 = *(const float4*)(qrow + kd * 32);
      float4 f1 = *(const float4*)(qrow + kd * 32 + 4);
      union { short8 s; unsigned u[4]; } tt;
      tt.u[0] = bfpack2(f0.x, f0.y);
      tt.u[1] = bfpack2(f0.z, f0.w);
      tt.u[2] = bfpack2(f1.x, f1.y);
      tt.u[3] = bfpack2(f1.z, f1.w);
      bq[sub][kd] = tt.s;
    }
  }

  floatx4 acc[2][8];
#pragma unroll
  for (int sub = 0; sub < 2; ++sub)
#pragma unroll
    for (int nc = 0; nc < 8; ++nc) acc[sub][nc] = (floatx4){0.f, 0.f, 0.f, 0.f};
  float m_run[2] = {-1e30f, -1e30f}, l_run[2] = {0.f, 0.f};

  const unsigned short* kb0 = Kb + (size_t)b * 64 * 8192;   // tile images
  const unsigned short* vb0 = Vt + (size_t)b * 64 * 8192;
  const int lo = lane * 8;            // lane*16B in shorts

  // stage(buf, step): each wave DMAs 1/8 of K and V (2KB+2KB) = 4 instrs
#define STAGE(BUF, S)                                                          \
  do {                                                                         \
    const unsigned short* kg_ = kb0 + (size_t)(S) * 8192 + w * 1024 + lo;      \
    const unsigned short* vg_ = vb0 + (size_t)(S) * 8192 + w * 1024 + lo;      \
    short* kl_ = &Klds[BUF][w * 1024];                                         \
    short* vl_ = &Vtlds[BUF][w * 1024];                                        \
    dma16(kg_, kl_);        dma16(kg_ + 512, kl_ + 512);                       \
    dma16(vg_, vl_);        dma16(vg_ + 512, vl_ + 512);                       \
  } while (0)

  // ---- prologue: stage s0 (and s0+1 into the other buffer) ----
  STAGE(s0 & 1, s0);
  if (s0 + 1 < s1) {
    STAGE((s0 + 1) & 1, s0 + 1);
    asm volatile("s_waitcnt vmcnt(4)" ::: "memory");   // s0's 4 done
  } else {
    asm volatile("s_waitcnt vmcnt(0)" ::: "memory");
  }
  __builtin_amdgcn_s_barrier();
  __builtin_amdgcn_sched_barrier(0);

  for (int s = s0; s < s1; ++s) {
    const int kt  = s * KB;
    const int cur = s & 1;
    const short* Kl = &Klds[cur][0];
    const short* Vl = &Vtlds[cur][0];
    const bool act = (kt <= q0 + w * 32 + 31);   // wave fully masked beyond

    floatx4 st[2][4];
    if (act) {
      // ---- S^T = K*Q^T for both subtiles; each A-frag read used twice ----
      __builtin_amdgcn_s_setprio(1);
#pragma unroll
      for (int kf = 0; kf < 4; ++kf) {
        floatx4 c0 = (floatx4){0.f, 0.f, 0.f, 0.f};
        floatx4 c1 = (floatx4){0.f, 0.f, 0.f, 0.f};
#pragma unroll
        for (int kd = 0; kd < 4; ++kd) {
          short8 a = *(const short8*)(&Kl[((kf * 16 + l15) << 7) + ((kd * 32 + quad * 8) ^ xk)]);
          c0 = __builtin_amdgcn_mfma_f32_16x16x32_bf16(a, bq[0][kd], c0, 0, 0, 0);
          c1 = __builtin_amdgcn_mfma_f32_16x16x32_bf16(a, bq[1][kd], c1, 0, 0, 0);
        }
        st[0][kf] = c0;
        st[1][kf] = c1;
      }
      __builtin_amdgcn_s_setprio(0);

      // ---- causal mask (boundary subtiles only) ----
#pragma unroll
      for (int sub = 0; sub < 2; ++sub) {
        if (kt + 63 > q0 + w * 32 + sub * 16) {
#pragma unroll
          for (int kf = 0; kf < 4; ++kf)
#pragma unroll
            for (int r = 0; r < 4; ++r) {
              int key = kt + kf * 16 + quad * 4 + r;
              if (key > qg[sub]) st[sub][kf][r] = -1e30f;
            }
        }
      }
    }

    // K[cur] fully consumed block-wide; its buffer becomes P scratch.
    __builtin_amdgcn_s_barrier();
    __builtin_amdgcn_sched_barrier(0);

    short8 pa[2][2];
    if (act) {
      // ---- online softmax + P roundtrip (through Klds[cur]) per subtile ----
      short* pw = &Klds[cur][(w * 16 + l15) << 6];   // wave-private 64-short row
#pragma unroll
      for (int sub = 0; sub < 2; ++sub) {
        float mx = st[sub][0][0];
#pragma unroll
        for (int kf = 0; kf < 4; ++kf)
#pragma unroll
          for (int r = 0; r < 4; ++r) mx = fmaxf(mx, st[sub][kf][r]);
        mx = fmaxf(mx, __shfl_xor(mx, 16, 64));
        mx = fmaxf(mx, __shfl_xor(mx, 32, 64));
        const float m_new = fmaxf(m_run[sub], mx);
        const bool  grow  = __any(m_new > m_run[sub]);

        float p[4][4];
        float tsum = 0.f;
#pragma unroll
        for (int kf = 0; kf < 4; ++kf)
#pragma unroll
          for (int r = 0; r < 4; ++r) {
            p[kf][r] = EXP2F((st[sub][kf][r] - m_new) * CSC);
            tsum += p[kf][r];
          }
        tsum += __shfl_xor(tsum, 16, 64);
        tsum += __shfl_xor(tsum, 32, 64);

        if (grow) {
          const float alpha = EXP2F((m_run[sub] - m_new) * CSC);
          l_run[sub] = l_run[sub] * alpha + tsum;
#pragma unroll
          for (int r = 0; r < 4; ++r) {
            const float ar = __shfl(alpha, quad * 4 + r, 64);
#pragma unroll
            for (int nc = 0; nc < 8; ++nc) acc[sub][nc][r] *= ar;
          }
        } else {
          l_run[sub] = l_run[sub] + tsum;   // m_new == m_run for every query
        }
        m_run[sub] = m_new;

        // P: C-layout -> A-layout; XOR-swizzled stride-64 rows (in-order per wave)
#pragma unroll
        for (int kf = 0; kf < 4; ++kf) {
          uint2 u;
          u.x = cvtpk(p[kf][0], p[kf][1]);
          u.y = cvtpk(p[kf][2], p[kf][3]);
          *(uint2*)(&pw[(kf * 16 + quad * 4) ^ xk]) = u;
        }
        __asm__ __volatile__("" ::: "memory");
        pa[sub][0] = *(const short8*)(&pw[(quad * 8) ^ xk]);
        pa[sub][1] = *(const short8*)(&pw[(32 + quad * 8) ^ xk]);
        __asm__ __volatile__("" ::: "memory");
      }

      // ---- O += P*V ; each B-frag read used by both subtiles ----
      __builtin_amdgcn_s_setprio(1);
#pragma unroll
      for (int nc = 0; nc < 8; ++nc) {
        short8 bv0 = *(const short8*)(&Vl[((nc * 16 + l15) << 6) + ((quad * 8) ^ xk)]);
        short8 bv1 = *(const short8*)(&Vl[((nc * 16 + l15) << 6) + ((32 + quad * 8) ^ xk)]);
        acc[0][nc] = __builtin_amdgcn_mfma_f32_16x16x32_bf16(pa[0][0], bv0, acc[0][nc], 0, 0, 0);
        acc[0][nc] = __builtin_amdgcn_mfma_f32_16x16x32_bf16(pa[0][1], bv1, acc[0][nc], 0, 0, 0);
        acc[1][nc] = __builtin_amdgcn_mfma_f32_16x16x32_bf16(pa[1][0], bv0, acc[1][nc], 0, 0, 0);
        acc[1][nc] = __builtin_amdgcn_mfma_f32_16x16x32_bf16(pa[1][1], bv1, acc[1][nc], 0, 0, 0);
      }
      __builtin_amdgcn_s_setprio(0);
    }

    // ---- pipeline advance: free both [cur] buffers, stage s+2, await s+1 ----
    asm volatile("s_waitcnt lgkmcnt(0)" ::: "memory");
    __builtin_amdgcn_s_barrier();               // all waves done with P/V[cur]
    __builtin_amdgcn_sched_barrier(0);
    if (s + 2 < s1) {
      STAGE(cur, s + 2);
      asm volatile("s_waitcnt vmcnt(4)" ::: "memory");   // s+1's 4 done
    } else if (s + 1 < s1) {
      asm volatile("s_waitcnt vmcnt(0)" ::: "memory");
    }
    __builtin_amdgcn_s_barrier();               // buf[(s+1)&1] visible to all
    __builtin_amdgcn_sched_barrier(0);
  }
#undef STAGE

  // ---- partial epilogue: unnormalized O + (m,l); slot == wid ----
  float* po = pO + (size_t)wid * 32768;
#pragma unroll
  for (int sub = 0; sub < 2; ++sub) {
#pragma unroll
    for (int r = 0; r < 4; ++r) {
      const int qrow = w * 32 + sub * 16 + quad * 4 + r;
      float* op = po + qrow * D_K + l15;
#pragma unroll
      for (int nc = 0; nc < 8; ++nc) op[nc * 16] = acc[sub][nc][r];
    }
    if (quad == 0) {
      const int qrow = w * 32 + sub * 16 + l15;
      ml[(size_t)wid * 512 + qrow * 2]     = m_run[sub];
      ml[(size_t)wid * 512 + qrow * 2 + 1] = l_run[sub];
    }
  }
}

// ======================= combine kernel =======================
// 256 blocks = (b*16 + t)*2 + d-half; up to 8 partials per 256-q tile.

__global__ __launch_bounds__(256)
void attn_combine(const float* __restrict__ ml, const float* __restrict__ pO,
                  float* __restrict__ O) {
  const int cb   = blockIdx.x;
  const int half = cb & 1;
  const int bt   = cb >> 1;
  const int b    = bt >> 4;
  const int t    = bt & 15;
  const float CSC = 0.12752041f;

  const int q  = threadIdx.x;         // 0..255
  const int dh = half * 64;

  // chunk slots for (b, t): nf full chunks + tail (t even)
  int cum = 0;
  for (int tt = 15; tt > t; --tt) cum += (tt + 1) >> 1;
  const int nf = (t + 1) >> 1;
  int slots[8];
  int ns = 0;
#pragma unroll
  for (int jj = 0; jj < 8; ++jj)
    if (jj < nf) { slots[ns] = b * 64 + cum + jj; ++ns; }
  if (!(t & 1)) { slots[ns] = NFULL + b * 8 + (7 - (t >> 1)); ++ns; }

  float m[8], l[8], wgt[8];
  float M = -1e30f;
#pragma unroll
  for (int i = 0; i < 8; ++i) {
    if (i < ns) {
      m[i] = ml[(size_t)slots[i] * 512 + q * 2];
      l[i] = ml[(size_t)slots[i] * 512 + q * 2 + 1];
      M = fmaxf(M, m[i]);
    }
  }
  float L = 0.f;
#pragma unroll
  for (int i = 0; i < 8; ++i)
    if (i < ns) { wgt[i] = EXP2F((m[i] - M) * CSC); L += wgt[i] * l[i]; }
  const float inv = 1.0f / L;

  float4 out[16];
#pragma unroll
  for (int v = 0; v < 16; ++v) out[v] = make_float4(0.f, 0.f, 0.f, 0.f);
#pragma unroll
  for (int i = 0; i < 8; ++i) {
    if (i < ns) {
      const float* src = pO + (size_t)slots[i] * 32768 + q * D_K + dh;
      const float wj = wgt[i];
#pragma unroll
      for (int v = 0; v < 16; ++v) {
        float4 f = *(const float4*)(src + v * 4);
        out[v].x += wj * f.x;  out[v].y += wj * f.y;
        out[v].z += wj * f.z;  out[v].w += wj * f.w;
      }
    }
  }
  float* dst = O + ((size_t)(b * S_LEN) + t * 256 + q) * D_K + dh;
#pragma unroll
  for (int v = 0; v < 16; ++v) {
    *(float4*)(dst + v * 4) = make_float4(out[v].x * inv, out[v].y * inv,
                                          out[v].z * inv, out[v].w * inv);
  }
}

// ======================= fallback (known-good, ws-too-small path) =======================

#define KT_STR 136
#define VT_STR 72
#define PT_STR 72

__global__ __launch_bounds__(256, 2)
void attn_fwd_fb(const float* __restrict__ Q, const float* __restrict__ K,
                 const float* __restrict__ V, float* __restrict__ O) {
  __shared__ __align__(16) short Klds[KB * KT_STR];
  __shared__ __align__(16) short Vtlds[D_K * VT_STR];
  __shared__ __align__(16) short Plds[4 * 16 * PT_STR];

  const int tid  = threadIdx.x;
  const int lane = tid & 63;
  const int w    = tid >> 6;
  const int l15  = lane & 15;
  const int quad = lane >> 4;

  const int bid = blockIdx.x;
  const int b   = bid & 7;
  const int qi  = 63 - (bid >> 3);
  const int q0  = qi * 64;

  const float CSC = 0.12752041f;

  const int    qg   = q0 + w * 16 + l15;
  const float* qrow = Q + (size_t)(b * S_LEN + qg) * D_K + quad * 8;
  short8 bq[4];
#pragma unroll
  for (int kd = 0; kd < 4; ++kd) {
    float4 f0 = *(const float4*)(qrow + kd * 32);
    float4 f1 = *(const float4*)(qrow + kd * 32 + 4);
    union { short8 s; unsigned u[4]; } t;
    t.u[0] = bfpack2(f0.x, f0.y);
    t.u[1] = bfpack2(f0.z, f0.w);
    t.u[2] = bfpack2(f1.x, f1.y);
    t.u[3] = bfpack2(f1.z, f1.w);
    bq[kd] = t.s;
  }

  floatx4 acc[8];
#pragma unroll
  for (int nc = 0; nc < 8; ++nc) acc[nc] = (floatx4){0.f, 0.f, 0.f, 0.f};
  float m_run = -1e30f, l_run = 0.f;

  const int d4 = tid & 31;
  const int kq = tid >> 5;
  const int nsteps = qi + 1;

  for (int s = 0; s < nsteps; ++s) {
    const int kt = s * KB;
#pragma unroll
    for (int r2 = 0; r2 < 2; ++r2) {
      const int row = r2 * 32 + kq * 4;
      const float* kp = K + (size_t)(b * S_LEN + kt + row) * D_K + d4 * 4;
      const float* vp = V + (size_t)(b * S_LEN + kt + row) * D_K + d4 * 4;
      float4 fk[4], fv[4];
#pragma unroll
      for (int i = 0; i < 4; ++i) {
        fk[i] = *(const float4*)(kp + i * D_K);
        fv[i] = *(const float4*)(vp + i * D_K);
      }
#pragma unroll
      for (int i = 0; i < 4; ++i) {
        uint2 u;
        u.x = bfpack2(fk[i].x, fk[i].y);
        u.y = bfpack2(fk[i].z, fk[i].w);
        *(uint2*)(&Klds[(row + i) * KT_STR + d4 * 4]) = u;
      }
#pragma unroll
      for (int c = 0; c < 4; ++c) {
        float e0 = ((const float*)&fv[0])[c];
        float e1 = ((const float*)&fv[1])[c];
        float e2 = ((const float*)&fv[2])[c];
        float e3 = ((const float*)&fv[3])[c];
        uint2 u;
        u.x = bfpack2(e0, e1);
        u.y = bfpack2(e2, e3);
        *(uint2*)(&Vtlds[(d4 * 4 + c) * VT_STR + row]) = u;
      }
    }
    __syncthreads();

    floatx4 st[4];
#pragma unroll
    for (int kf = 0; kf < 4; ++kf) {
      floatx4 cc = (floatx4){0.f, 0.f, 0.f, 0.f};
#pragma unroll
      for (int kd = 0; kd < 4; ++kd) {
        short8 a = *(const short8*)(&Klds[(kf * 16 + l15) * KT_STR + kd * 32 + quad * 8]);
        cc = __builtin_amdgcn_mfma_f32_16x16x32_bf16(a, bq[kd], cc, 0, 0, 0);
      }
      st[kf] = cc;
    }

    if (s == nsteps - 1) {
#pragma unroll
      for (int kf = 0; kf < 4; ++kf)
#pragma unroll
        for (int rr = 0; rr < 4; ++rr) {
          int key = kt + kf * 16 + quad * 4 + rr;
          if (key > qg) st[kf][rr] = -1e30f;
        }
    }

    float mx = st[0][0];
#pragma unroll
    for (int kf = 0; kf < 4; ++kf)
#pragma unroll
      for (int rr = 0; rr < 4; ++rr) mx = fmaxf(mx, st[kf][rr]);
    mx = fmaxf(mx, __shfl_xor(mx, 16, 64));
    mx = fmaxf(mx, __shfl_xor(mx, 32, 64));
    const float m_new = fmaxf(m_run, mx);
    const float alpha = EXP2F((m_run - m_new) * CSC);

    float p[4][4];
    float tsum = 0.f;
#pragma unroll
    for (int kf = 0; kf < 4; ++kf)
#pragma unroll
      for (int rr = 0; rr < 4; ++rr) {
        p[kf][rr] = EXP2F((st[kf][rr] - m_new) * CSC);
        tsum += p[kf][rr];
      }
    tsum += __shfl_xor(tsum, 16, 64);
    tsum += __shfl_xor(tsum, 32, 64);
    l_run = l_run * alpha + tsum;
    m_run = m_new;

#pragma unroll
    for (int rr = 0; rr < 4; ++rr) {
      const float ar = __shfl(alpha, quad * 4 + rr, 64);
#pragma unroll
      for (int nc = 0; nc < 8; ++nc) acc[nc][rr] *= ar;
    }

    short* pw = &Plds[(w * 16 + l15) * PT_STR];
#pragma unroll
    for (int kf = 0; kf < 4; ++kf) {
      uint2 u;
      u.x = bfpack2(p[kf][0], p[kf][1]);
      u.y = bfpack2(p[kf][2], p[kf][3]);
      *(uint2*)(&pw[kf * 16 + quad * 4]) = u;
    }
    __asm__ __volatile__("" ::: "memory");
    short8 pa0 = *(const short8*)(&pw[quad * 8]);
    short8 pa1 = *(const short8*)(&pw[32 + quad * 8]);

#pragma unroll
    for (int nc = 0; nc < 8; ++nc) {
      short8 bv0 = *(const short8*)(&Vtlds[(nc * 16 + l15) * VT_STR + quad * 8]);
      acc[nc] = __builtin_amdgcn_mfma_f32_16x16x32_bf16(pa0, bv0, acc[nc], 0, 0, 0);
      short8 bv1 = *(const short8*)(&Vtlds[(nc * 16 + l15) * VT_STR + 32 + quad * 8]);
      acc[nc] = __builtin_amdgcn_mfma_f32_16x16x32_bf16(pa1, bv1, acc[nc], 0, 0, 0);
    }
    __syncthreads();
  }

#pragma unroll
  for (int rr = 0; rr < 4; ++rr) {
    const float lr  = __shfl(l_run, quad * 4 + rr, 64);
    const float inv = 1.0f / lr;
    const int qout  = q0 + w * 16 + quad * 4 + rr;
    float* op = O + (size_t)(b * S_LEN + qout) * D_K + l15;
#pragma unroll
    for (int nc = 0; nc < 8; ++nc) op[nc * 16] = acc[nc][rr] * inv;
  }
}

// ======================= launch =======================

extern "C" void kernel_launch(void* const* d_in, const int* in_sizes, int n_in,
                              void* d_out, int out_size, void* d_ws, size_t ws_size,
                              hipStream_t stream) {
  const float* Q = (const float*)d_in[0];
  const float* K = (const float*)d_in[1];
  const float* V = (const float*)d_in[2];
  float* O = (float*)d_out;

  const size_t elems = (size_t)B_SZ * S_LEN * D_K;   // 4.19M

  // ws layout (bytes):
  //   0          : ml    [576 slots][256 q][m,l]      =  1,179,648
  //   1,179,648  : partO [576 slots][256 q][128 d]f32 = 75,497,472
  //   76,677,120 : Kb tile-images bf16                =  8,388,608
  //   85,065,728 : Vt tile-images bf16                =  8,388,608
  //   need ~93.5 MB
  const size_t off_ml = 0;
  const size_t off_po = (size_t)NCHUNK * 512 * 4;
  const size_t off_kb = off_po + (size_t)NCHUNK * 32768 * 4;
  const size_t off_vt = off_kb + elems * 2;
  const size_t need   = off_vt + elems * 2;

  if (ws_size >= need) {
    char* ws = (char*)d_ws;
    float*          mlp = (float*)(ws + off_ml);
    float*          po  = (float*)(ws + off_po);
    unsigned short* Kbp = (unsigned short*)(ws + off_kb);
    unsigned short* Vtp = (unsigned short*)(ws + off_vt);

    prep<<<dim3(B_SZ * 64), dim3(256), 0, stream>>>(K, V, Kbp, Vtp);
    attn_worker<<<dim3(NCHUNK), dim3(512), 0, stream>>>(Q, Kbp, Vtp, mlp, po);
    attn_combine<<<dim3(256), dim3(256), 0, stream>>>(mlp, po, O);
  } else {
    attn_fwd_fb<<<dim3(512), dim3(256), 0, stream>>>(Q, K, V, O);
  }
}